// Round 3
// baseline (85.375 us; speedup 1.0000x reference)
//
#include <hip/hip_runtime.h>
#include <math.h>

// Problem constants: N=8192, C=19, M=10, K=64
#define NN   8192
#define KK   64
#define CMV  190          // C*M
#define PV_ELEMS (CMV*KK)

// ---------- ws layout (in bytes from d_ws) ----------
// [0]                : int flag  (1 => proto_var is all 1.0f, fast path valid)
// [256 .. )          : float Lrow[NN]         (sum_k log2(1+xvar))
// [256+NN*4 .. )     : float iv[NN*KK]        (1/(1+xvar))

//======================================================================
// Kernel 1: flag = all(pvar == 1.0f)   (single block, ballot reduce)
//======================================================================
__global__ __launch_bounds__(256)
void flag_kernel(const float* __restrict__ pvar, int* __restrict__ flag)
{
  __shared__ int bad_s[4];
  int bad = 0;
  for (int i = threadIdx.x; i < PV_ELEMS; i += 256)
    bad |= (pvar[i] != 1.0f) ? 1 : 0;
  unsigned long long m = __ballot(bad);
  if ((threadIdx.x & 63) == 0) bad_s[threadIdx.x >> 6] = (m != 0ull);
  __syncthreads();
  if (threadIdx.x == 0)
    *flag = (bad_s[0] | bad_s[1] | bad_s[2] | bad_s[3]) ? 0 : 1;
}

//======================================================================
// Kernel 2: per-row precompute (used only by fast path)
//   iv[n,k] = 1/(1+xvar[n,k]);  Lrow[n] = sum_k log2(1+xvar[n,k])
// One wave == one row (64 lanes == 64 k's).
//======================================================================
__global__ __launch_bounds__(256)
void row_kernel(const float* __restrict__ xvar,
                float* __restrict__ iv, float* __restrict__ Lrow)
{
  const int gid  = blockIdx.x * 256 + threadIdx.x;  // one element
  const int n    = gid >> 6;
  const int lane = threadIdx.x & 63;
  float v = xvar[gid] + 1.0f;
  iv[gid] = __builtin_amdgcn_rcpf(v);
  float lg = __builtin_amdgcn_logf(v);   // log2
#pragma unroll
  for (int s = 32; s; s >>= 1) lg += __shfl_xor(lg, s, 64);
  if (lane == 0) Lrow[n] = lg;
}

//======================================================================
// Kernel 3: FAST main (pvar==1). thread = cm, TNF rows per block.
//   out[n,cm] = -0.5/64 * ( sum_k (p-x)^2*iv  +  ln2 * Lrow[n] )
//======================================================================
#define TNF 8
#define NTHREADS 192

__global__ __launch_bounds__(NTHREADS)
void fast_kernel(const float* __restrict__ x,
                 const float* __restrict__ proto,
                 const float* __restrict__ ivg,
                 const float* __restrict__ Lg,
                 const int* __restrict__ flag,
                 float* __restrict__ out)
{
  if (!*flag) return;   // uniform across the block; taken before any barrier

  __shared__ float xs [TNF * KK];
  __shared__ float ivs[TNF * KK];
  __shared__ float Ls [TNF];

  const int tid = threadIdx.x;
  const int n0  = blockIdx.x * TNF;

  {
    const float4* gx = (const float4*)(x   + (size_t)n0 * KK);
    const float4* gi = (const float4*)(ivg + (size_t)n0 * KK);
    if (tid < TNF * KK / 4) {            // 128 float4's
      ((float4*)xs )[tid] = gx[tid];
      ((float4*)ivs)[tid] = gi[tid];
    }
    if (tid < TNF) Ls[tid] = Lg[n0 + tid];
  }
  __syncthreads();

  const int cm = tid;
  if (cm >= CMV) return;

  // Prototype row in registers (64 VGPRs), loaded once per block.
  float pc[KK];
  {
    const float4* pp = (const float4*)(proto + (size_t)cm * KK);
#pragma unroll
    for (int q = 0; q < 16; ++q) {
      float4 t = pp[q];
      pc[4*q+0] = t.x; pc[4*q+1] = t.y; pc[4*q+2] = t.z; pc[4*q+3] = t.w;
    }
  }

  const float c1  = -0.5f / (float)KK;
  const float ln2 = 0.69314718055994530942f;

#pragma unroll
  for (int n = 0; n < TNF; ++n) {
    float acc = 0.f;
#pragma unroll
    for (int kc = 0; kc < 4; ++kc) {
      float xk[16], ik[16];
      const float4* sx = (const float4*)(xs  + n * KK + kc * 16);
      const float4* si = (const float4*)(ivs + n * KK + kc * 16);
#pragma unroll
      for (int q = 0; q < 4; ++q) {
        float4 t = sx[q];
        xk[4*q+0] = t.x; xk[4*q+1] = t.y; xk[4*q+2] = t.z; xk[4*q+3] = t.w;
        float4 u = si[q];
        ik[4*q+0] = u.x; ik[4*q+1] = u.y; ik[4*q+2] = u.z; ik[4*q+3] = u.w;
      }
#pragma unroll
      for (int i = 0; i < 16; ++i) {
        float d = pc[kc*16 + i] - xk[i];
        acc = fmaf(d * ik[i], d, acc);
      }
    }
    out[(size_t)(n0 + n) * CMV + cm] = c1 * (acc + ln2 * Ls[n]);
  }
}

//======================================================================
// Kernel 4: SLOW fallback (general pvar) — round-1 kernel, gated on !flag.
//======================================================================
#define TN 16

#define COMB(i, s)                                          \
  do {                                                      \
    num[i] = num[i] * den[(i)+(s)] + num[(i)+(s)] * den[i]; \
    den[i] = den[i] * den[(i)+(s)];                         \
  } while (0)

__global__ __launch_bounds__(NTHREADS)
void slow_kernel(const float* __restrict__ x,
                 const float* __restrict__ xvar,
                 const float* __restrict__ proto,
                 const float* __restrict__ pvar,
                 const int* __restrict__ flag,
                 float* __restrict__ out)
{
  if (*flag) return;   // uniform across the block; taken before any barrier

  __shared__ float xs[TN * KK];
  __shared__ float xvs[TN * KK];

  const int tid = threadIdx.x;
  const int n0  = blockIdx.x * TN;

  {
    const float4* gx  = (const float4*)(x    + (size_t)n0 * KK);
    const float4* gxv = (const float4*)(xvar + (size_t)n0 * KK);
    float4* sx  = (float4*)xs;
    float4* sxv = (float4*)xvs;
    for (int i = tid; i < TN * KK / 4; i += NTHREADS) {
      sx[i]  = gx[i];
      sxv[i] = gxv[i];
    }
  }
  __syncthreads();

  const int cm = tid;
  if (cm >= CMV) return;

  float acc_frac[TN];
  float acc_log2[TN];
#pragma unroll
  for (int n = 0; n < TN; ++n) { acc_frac[n] = 0.f; acc_log2[n] = 0.f; }

#pragma unroll
  for (int kc = 0; kc < 4; ++kc) {
    const int kb = kc * 16;
    float pc[16], pvc[16];
    {
      const float4* pp  = (const float4*)(proto + (size_t)cm * KK + kb);
      const float4* ppv = (const float4*)(pvar  + (size_t)cm * KK + kb);
#pragma unroll
      for (int q = 0; q < 4; ++q) {
        float4 t = pp[q];
        pc[4*q+0] = t.x; pc[4*q+1] = t.y; pc[4*q+2] = t.z; pc[4*q+3] = t.w;
        float4 u = ppv[q];
        pvc[4*q+0] = u.x; pvc[4*q+1] = u.y; pvc[4*q+2] = u.z; pvc[4*q+3] = u.w;
      }
    }

#pragma unroll
    for (int n = 0; n < TN; ++n) {
      float xk[16], xvk[16];
      {
        const float4* sx4  = (const float4*)(xs  + n * KK + kb);
        const float4* sxv4 = (const float4*)(xvs + n * KK + kb);
#pragma unroll
        for (int q = 0; q < 4; ++q) {
          float4 t = sx4[q];
          xk[4*q+0] = t.x; xk[4*q+1] = t.y; xk[4*q+2] = t.z; xk[4*q+3] = t.w;
          float4 u = sxv4[q];
          xvk[4*q+0] = u.x; xvk[4*q+1] = u.y; xvk[4*q+2] = u.z; xvk[4*q+3] = u.w;
        }
      }

      float num[16], den[16];
#pragma unroll
      for (int i = 0; i < 16; ++i) {
        float d = pc[i] - xk[i];
        num[i] = d * d;
        den[i] = pvc[i] + xvk[i];
      }
      COMB(0,1);  COMB(2,1);  COMB(4,1);  COMB(6,1);
      COMB(8,1);  COMB(10,1); COMB(12,1); COMB(14,1);
      COMB(0,2);  COMB(4,2);  COMB(8,2);  COMB(12,2);
      COMB(0,4);  COMB(8,4);
      COMB(0,8);

      acc_frac[n] += num[0] * __builtin_amdgcn_rcpf(den[0]);
      acc_log2[n] += __builtin_amdgcn_logf(den[0]);
    }
  }

  const float c1  = -0.5f / (float)KK;
  const float ln2 = 0.69314718055994530942f;
#pragma unroll
  for (int n = 0; n < TN; ++n) {
    out[(size_t)(n0 + n) * CMV + cm] = c1 * (acc_frac[n] + ln2 * acc_log2[n]);
  }
}

//======================================================================
extern "C" void kernel_launch(void* const* d_in, const int* in_sizes, int n_in,
                              void* d_out, int out_size, void* d_ws, size_t ws_size,
                              hipStream_t stream) {
  const float* x     = (const float*)d_in[0];
  const float* xvar  = (const float*)d_in[1];
  const float* proto = (const float*)d_in[2];
  const float* pvar  = (const float*)d_in[3];
  float* out = (float*)d_out;

  char* ws = (char*)d_ws;
  int*   ws_flag = (int*)ws;
  float* ws_L    = (float*)(ws + 256);
  float* ws_iv   = (float*)(ws + 256 + NN * sizeof(float));

  flag_kernel<<<1, 256, 0, stream>>>(pvar, ws_flag);
  row_kernel <<<NN * KK / 256, 256, 0, stream>>>(xvar, ws_iv, ws_L);
  fast_kernel<<<NN / TNF, NTHREADS, 0, stream>>>(x, proto, ws_iv, ws_L, ws_flag, out);
  slow_kernel<<<NN / TN, NTHREADS, 0, stream>>>(x, xvar, proto, pvar, ws_flag, out);
}